// Round 4
// baseline (576.728 us; speedup 1.0000x reference)
//
#include <hip/hip_runtime.h>

// Problem constants (from reference): D=128, B=2048, C=512.
// Output: [B, 2C] fp32 where out[b,0:C] = (size==D ? buffer[head,b,:] : 0),
//         out[b,C:2C] = x[b,:].
constexpr int D = 128;
constexpr int B = 2048;
constexpr int C = 512;
constexpr int C4 = C / 4;        // 128 float4 per half-row
constexpr int W4 = 2 * C4;       // 256 float4 per output row
constexpr int TOTAL4 = B * W4;   // 524288 float4 total

// Clang-native 16B vector — required by __builtin_nontemporal_store
// (HIP_vector_type float4 is a class and is rejected).
typedef float v4f __attribute__((ext_vector_type(4)));

__global__ __launch_bounds__(256)
void causal_queue_concat(const v4f* __restrict__ x,
                         const v4f* __restrict__ buf,
                         const int* __restrict__ size_p,
                         const int* __restrict__ head_p,
                         v4f* __restrict__ out) {
    // Uniform scalar state — load once, wave-uniform (compiler emits s_load).
    const bool full = (size_p[0] == D);
    const int  head = head_p[0];

    const int i = blockIdx.x * blockDim.x + threadIdx.x;   // [0, TOTAL4)
    const int b  = i >> 8;        // / W4 (=256)
    const int c4 = i & (W4 - 1);  // % 256

    v4f v;
    if (c4 < C4) {
        // x_past half: buffer[head, b, :] when full, else zeros.
        // Wave-uniform branch: 64 consecutive i share the same half.
        if (full) {
            v = buf[(size_t)head * (B * C4) + (size_t)b * C4 + c4];
        } else {
            v = (v4f){0.f, 0.f, 0.f, 0.f};
        }
    } else {
        // x half
        v = x[(size_t)b * C4 + (c4 - C4)];
    }
    // Streaming write, no reuse — nontemporal hint.
    __builtin_nontemporal_store(v, &out[i]);
}

extern "C" void kernel_launch(void* const* d_in, const int* in_sizes, int n_in,
                              void* d_out, int out_size, void* d_ws, size_t ws_size,
                              hipStream_t stream) {
    const v4f* x     = (const v4f*)d_in[0];   // [B, C] fp32
    const v4f* buf   = (const v4f*)d_in[1];   // [D, B, C] fp32
    const int* sizep = (const int*)d_in[2];   // scalar
    const int* headp = (const int*)d_in[3];   // scalar
    v4f*       out   = (v4f*)d_out;           // [B, 2C] fp32

    constexpr int BLOCK = 256;
    constexpr int GRID  = TOTAL4 / BLOCK;           // 2048 blocks
    causal_queue_concat<<<GRID, BLOCK, 0, stream>>>(x, buf, sizep, headp, out);
}